// Round 2
// baseline (99361.615 us; speedup 1.0000x reference)
//
#include <hip/hip_runtime.h>
#include <cmath>

#define NV 32000
#define NE 512
#define NH 1024
#define NTX 2048
#define NTY 512
#define NWG 256
#define TPB 512

// encoder uses phases 1 .. NTX+3 (init + 2049 loop + fc1); decoder continues after
#define ENC_PH ((unsigned)(NTX + 3))

typedef float vf4 __attribute__((ext_vector_type(4)));
typedef unsigned long long u64;

// ---------- helpers ----------
__device__ inline float sigm(float x){ return 1.0f/(1.0f + expf(-x)); }

__device__ inline float wred(float v){
  #pragma unroll
  for (int m = 32; m; m >>= 1) v += __shfl_xor(v, m, 64);
  return v;
}

// plain (cached) 16-float load, 16B-vectorized
__device__ inline void ld16(const float* __restrict__ p, float* d){
  vf4 a = *(const vf4*)p, b = *(const vf4*)(p+4), c = *(const vf4*)(p+8), e = *(const vf4*)(p+12);
  d[0]=a.x; d[1]=a.y; d[2]=a.z; d[3]=a.w;
  d[4]=b.x; d[5]=b.y; d[6]=b.z; d[7]=b.w;
  d[8]=c.x; d[9]=c.y; d[10]=c.z; d[11]=c.w;
  d[12]=e.x; d[13]=e.y; d[14]=e.z; d[15]=e.w;
}

// coherent (agent-scope, LLC-served) 16-float load: correct across XCDs
__device__ inline void coh16(const float* p, float* d){
  #pragma unroll
  for (int k = 0; k < 16; ++k)
    d[k] = __hip_atomic_load(p + k, __ATOMIC_RELAXED, __HIP_MEMORY_SCOPE_AGENT);
}

__device__ inline void sto(float* p, float v){
  __hip_atomic_store(p, v, __ATOMIC_RELAXED, __HIP_MEMORY_SCOPE_AGENT);
}

// grid barrier v3: tree barrier, contention-free broadcast, relaxed polling.
//  - arrival: release-store of monotonic phase to own packed flag (256 x u32)
//  - detection: WG 0 only polls the packed flags (one reader per line)
//  - broadcast: WG 0 publishes phase to 256 per-WG slots padded to 128 B
//    (one line per WG); each WG spins on ITS OWN line (64 lanes same addr
//    coalesce to 1 request) -> no same-line fan-in at the LLC.
//  - all polls RELAXED; single agent acquire fence at exit.
__device__ inline void gbar(unsigned* arrive, unsigned* bcast, unsigned ph){
  __syncthreads();
  const int tid = threadIdx.x, wg = blockIdx.x;
  if (tid == 0)
    __hip_atomic_store(&arrive[wg], ph, __ATOMIC_RELEASE, __HIP_MEMORY_SCOPE_AGENT);
  if (wg == 0 && tid < 64){
    const int base = tid * 4;
    for (;;){
      unsigned ok = 1u;
      #pragma unroll
      for (int k = 0; k < 4; ++k)
        ok &= (__hip_atomic_load(&arrive[base + k], __ATOMIC_RELAXED, __HIP_MEMORY_SCOPE_AGENT) >= ph) ? 1u : 0u;
      if (__all((int)ok)) break;
      __builtin_amdgcn_s_sleep(1);
    }
    #pragma unroll
    for (int k = 0; k < 4; ++k)
      __hip_atomic_store(&bcast[(size_t)(base + k) * 32], ph, __ATOMIC_RELAXED, __HIP_MEMORY_SCOPE_AGENT);
  }
  if (tid < 64){
    while (__hip_atomic_load(&bcast[(size_t)wg * 32], __ATOMIC_RELAXED, __HIP_MEMORY_SCOPE_AGENT) < ph)
      __builtin_amdgcn_s_sleep(1);
  }
  __builtin_amdgcn_fence(__ATOMIC_ACQUIRE, "agent");
  __syncthreads();
}

// ws layout (bytes):
//   0     : arrive[256] u32 (packed, 1 KB)
//   1024  : bcast[256][32] u32 (128 B stride per WG, 32 KB)  -> ends 33792
//   33792 : h0buf[2][1024] f32 (8 KB)
//   41984 : h1buf[2][1024] f32 (8 KB)
//   50176 : ysbuf[2][1024] f32 (8 KB)
//   58368 : f1buf[1024] f32 (4 KB)
//   62464 : f2buf[1024] f32 (4 KB)
//   66560 : parts[256] u64 (2 KB)

// ---------- encoder: persistent, layers 0/1 pipelined, + fc1/fc2 ----------
__global__ __launch_bounds__(TPB, 2) void enc_kernel(
    const int* __restrict__ x, const float* __restrict__ emb,
    const float* __restrict__ Wih0, const float* __restrict__ Whh0, const float* __restrict__ b0,
    const float* __restrict__ Wih1, const float* __restrict__ Whh1, const float* __restrict__ b1,
    const float* __restrict__ fc1w, const float* __restrict__ fc1b,
    const float* __restrict__ fc2w, const float* __restrict__ fc2b,
    char* __restrict__ ws)
{
  unsigned* arrive = (unsigned*)ws;
  unsigned* bcast  = (unsigned*)(ws + 1024);
  float* h0buf = (float*)(ws + 33792);
  float* h1buf = h0buf + 2048;
  float* ysbuf = h1buf + 2048;
  float* f1buf = ysbuf + 2048;
  float* f2buf = f1buf + 1024;

  const int tid = threadIdx.x, wg = blockIdx.x;
  const int wid = tid >> 6, lane = tid & 63;
  const bool isA = (wid < 4);          // waves 0-3: layer0, waves 4-7: layer1
  const int j = wg*4 + (wid & 3);      // 0..1023 : hidden index owned by this wave
  unsigned ph = 0;

  // register-resident weights (shared arrays across branches -> one allocation)
  float wa[4][16], wb[4][16], bias[4];
  if (isA){
    #pragma unroll
    for (int g = 0; g < 4; ++g){
      ld16(Whh0 + (size_t)(j + g*1024)*1024 + lane*16, wa[g]);
      const float* r2 = Wih0 + (size_t)(j + g*1024)*512 + lane*8;
      vf4 u0 = *(const vf4*)r2, u1 = *(const vf4*)(r2+4);
      wb[g][0]=u0.x; wb[g][1]=u0.y; wb[g][2]=u0.z; wb[g][3]=u0.w;
      wb[g][4]=u1.x; wb[g][5]=u1.y; wb[g][6]=u1.z; wb[g][7]=u1.w;
      #pragma unroll
      for (int k = 8; k < 16; ++k) wb[g][k] = 0.f;
      bias[g] = b0[j + g*1024];
    }
  } else {
    #pragma unroll
    for (int g = 0; g < 4; ++g){
      ld16(Wih1 + (size_t)(j + g*1024)*1024 + lane*16, wa[g]);
      ld16(Whh1 + (size_t)(j + g*1024)*1024 + lane*16, wb[g]);
      bias[g] = b1[j + g*1024];
    }
  }

  float c = 0.f;
  if (lane == 0){
    if (isA) sto(&h0buf[j], 0.f);
    else     sto(&h1buf[j], 0.f);
  }
  ph++; gbar(arrive, bcast, ph);

  // embedding prefetch for t = 0
  float xe[8] = {0,0,0,0,0,0,0,0};
  if (isA){
    const float* e = emb + (size_t)x[0]*NE + lane*8;
    vf4 a = *(const vf4*)e, b2 = *(const vf4*)(e+4);
    xe[0]=a.x; xe[1]=a.y; xe[2]=a.z; xe[3]=a.w;
    xe[4]=b2.x; xe[5]=b2.y; xe[6]=b2.z; xe[7]=b2.w;
  }

  for (int t = 0; t <= NTX; ++t){
    if (isA){
      if (t < NTX){
        float hs[16]; coh16(h0buf + (t&1)*1024 + lane*16, hs);
        float xc[8];
        #pragma unroll
        for (int k = 0; k < 8; ++k) xc[k] = xe[k];
        if (t + 1 < NTX){    // prefetch next embedding row
          const float* e = emb + (size_t)x[t+1]*NE + lane*8;
          vf4 a = *(const vf4*)e, b2 = *(const vf4*)(e+4);
          xe[0]=a.x; xe[1]=a.y; xe[2]=a.z; xe[3]=a.w;
          xe[4]=b2.x; xe[5]=b2.y; xe[6]=b2.z; xe[7]=b2.w;
        }
        float p[4];
        #pragma unroll
        for (int g = 0; g < 4; ++g){
          float s = 0.f;
          #pragma unroll
          for (int k = 0; k < 8; ++k)  s += wb[g][k]*xc[k];
          #pragma unroll
          for (int k = 0; k < 16; ++k) s += wa[g][k]*hs[k];
          p[g] = s;
        }
        #pragma unroll
        for (int g = 0; g < 4; ++g) p[g] = wred(p[g]) + bias[g];
        float ig = sigm(p[0]), fg = sigm(p[1]), gg = tanhf(p[2]), og = sigm(p[3]);
        c = fg*c + ig*gg;
        float hn = og * tanhf(c);
        if (lane == 0){
          sto(&h0buf[((t&1)^1)*1024 + j], hn);
          sto(&ysbuf[(t&1)*1024 + j], hn);
        }
      }
    } else {
      if (t >= 1){
        const int t1 = t - 1;
        float ys[16]; coh16(ysbuf + (t1&1)*1024 + lane*16, ys);
        float hs[16]; coh16(h1buf + (t1&1)*1024 + lane*16, hs);
        float p[4];
        #pragma unroll
        for (int g = 0; g < 4; ++g){
          float s = 0.f;
          #pragma unroll
          for (int k = 0; k < 16; ++k) s += wa[g][k]*ys[k];
          #pragma unroll
          for (int k = 0; k < 16; ++k) s += wb[g][k]*hs[k];
          p[g] = s;
        }
        #pragma unroll
        for (int g = 0; g < 4; ++g) p[g] = wred(p[g]) + bias[g];
        float ig = sigm(p[0]), fg = sigm(p[1]), gg = tanhf(p[2]), og = sigm(p[3]);
        c = fg*c + ig*gg;
        float hn = og * tanhf(c);
        if (lane == 0) sto(&h1buf[((t1&1)^1)*1024 + j], hn);
      }
    }
    ph++; gbar(arrive, bcast, ph);
  }

  // fc1: h_last is h1buf parity 0 (last write t1=2047 -> wp=0)
  if (isA){
    float hs[16]; coh16(h1buf + lane*16, hs);
    float wv[16]; ld16(fc1w + (size_t)j*1024 + lane*16, wv);
    float s = 0.f;
    #pragma unroll
    for (int k = 0; k < 16; ++k) s += wv[k]*hs[k];
    s = wred(s) + fc1b[j];
    if (lane == 0) sto(&f1buf[j], fmaxf(s, 0.f));
  }
  ph++; gbar(arrive, bcast, ph);
  if (isA){
    float fs[16]; coh16(f1buf + lane*16, fs);
    float wv[16]; ld16(fc2w + (size_t)j*1024 + lane*16, wv);
    float s = 0.f;
    #pragma unroll
    for (int k = 0; k < 16; ++k) s += wv[k]*fs[k];
    s = wred(s) + fc2b[j];
    if (lane == 0) sto(&f2buf[j], fmaxf(s, 0.f));
  }
  // f2buf visibility to dec_kernel: kernel dispatch boundary (stream-ordered)
}

// ---------- decoder: persistent, 511 greedy steps ----------
__global__ __launch_bounds__(TPB, 2) void dec_kernel(
    const int* __restrict__ y,
    const float* __restrict__ dWih0, const float* __restrict__ dWhh0, const float* __restrict__ db0,
    const float* __restrict__ dWih1, const float* __restrict__ dWhh1, const float* __restrict__ db1,
    const float* __restrict__ out_w, const float* __restrict__ out_b,
    float* __restrict__ out, char* __restrict__ ws)
{
  unsigned* arrive = (unsigned*)ws;     // continue encoder's monotonic phases
  unsigned* bcast  = (unsigned*)(ws + 1024);
  float* h0buf = (float*)(ws + 33792);
  float* h1buf = h0buf + 2048;
  float* f2buf = h1buf + 2048 + 2048 + 1024;      // skip ysbuf, f1buf
  u64* parts   = (u64*)(ws + 66560);

  const int tid = threadIdx.x, wg = blockIdx.x;
  const int wid = tid >> 6, lane = tid & 63;
  const bool isA = (wid < 4);
  const int j = wg*4 + (wid & 3);
  unsigned ph = ENC_PH;                // encoder's final flag value

  float wa[4][16], wb[4][16], bias[4], wx[4];
  if (isA){
    #pragma unroll
    for (int g = 0; g < 4; ++g){
      ld16(dWhh0 + (size_t)(j + g*1024)*1024 + lane*16, wa[g]);
      #pragma unroll
      for (int k = 0; k < 16; ++k) wb[g][k] = 0.f;
      wx[g]   = dWih0[j + g*1024];
      bias[g] = db0[j + g*1024];
    }
  } else {
    #pragma unroll
    for (int g = 0; g < 4; ++g){
      ld16(dWih1 + (size_t)(j + g*1024)*1024 + lane*16, wa[g]);
      ld16(dWhh1 + (size_t)(j + g*1024)*1024 + lane*16, wb[g]);
      bias[g] = db1[j + g*1024];
      wx[g] = 0.f;
    }
  }

  float c = f2buf[j];                 // h and c both init to f2
  if (lane == 0){
    if (isA) sto(&h0buf[j], c);
    else     sto(&h1buf[j], c);
  }
  const float y0f = (float)y[0];
  ph++; gbar(arrive, bcast, ph);

  __shared__ u64 sbest[8];

  for (int s = 0; s < NTY - 1; ++s){
    const int rp = s & 1, wp = rp ^ 1;

    // ---- phase A: layer0 cell (group A) ----
    if (isA){
      float xt;
      if (s == 0) xt = y0f;
      else {
        // redundant argmax reduction of 256 WG-partials (written last phase C)
        u64 b = 0ull;
        #pragma unroll
        for (int q = 0; q < 4; ++q){
          u64 v = __hip_atomic_load(&parts[lane + 64*q], __ATOMIC_RELAXED, __HIP_MEMORY_SCOPE_AGENT);
          if (v > b) b = v;
        }
        #pragma unroll
        for (int m = 32; m; m >>= 1){
          u64 v = __shfl_xor(b, m, 64);
          if (v > b) b = v;
        }
        unsigned row = ~(unsigned)(b & 0xFFFFFFFFull);
        xt = (float)row;
      }
      float hs[16]; coh16(h0buf + rp*1024 + lane*16, hs);
      float p[4];
      #pragma unroll
      for (int g = 0; g < 4; ++g){
        float sm = 0.f;
        #pragma unroll
        for (int k = 0; k < 16; ++k) sm += wa[g][k]*hs[k];
        p[g] = sm;
      }
      #pragma unroll
      for (int g = 0; g < 4; ++g) p[g] = wred(p[g]) + wx[g]*xt + bias[g];
      float ig = sigm(p[0]), fg = sigm(p[1]), gg = tanhf(p[2]), og = sigm(p[3]);
      c = fg*c + ig*gg;
      float hn = og * tanhf(c);
      if (lane == 0) sto(&h0buf[wp*1024 + j], hn);
    }
    ph++; gbar(arrive, bcast, ph);

    // ---- phase B: layer1 cell (group B) ----
    if (!isA){
      float u[16];  coh16(h0buf + wp*1024 + lane*16, u);
      float hs[16]; coh16(h1buf + rp*1024 + lane*16, hs);
      float p[4];
      #pragma unroll
      for (int g = 0; g < 4; ++g){
        float sm = 0.f;
        #pragma unroll
        for (int k = 0; k < 16; ++k) sm += wa[g][k]*u[k];
        #pragma unroll
        for (int k = 0; k < 16; ++k) sm += wb[g][k]*hs[k];
        p[g] = sm;
      }
      #pragma unroll
      for (int g = 0; g < 4; ++g) p[g] = wred(p[g]) + bias[g];
      float ig = sigm(p[0]), fg = sigm(p[1]), gg = tanhf(p[2]), og = sigm(p[3]);
      c = fg*c + ig*gg;
      float hn = og * tanhf(c);
      if (lane == 0) sto(&h1buf[wp*1024 + j], hn);
    }
    ph++; gbar(arrive, bcast, ph);

    // ---- phase C: logits row matvecs + partial argmax (all waves) ----
    {
      float hv[16]; coh16(h1buf + wp*1024 + lane*16, hv);
      u64 best = 0ull;
      float* orow = out + (size_t)(s + 1)*NV;
      for (int idx = wid; idx < 125; idx += 8){
        const int row = wg*125 + idx;
        float wv[16]; ld16(out_w + (size_t)row*1024 + lane*16, wv);
        float pp = 0.f;
        #pragma unroll
        for (int k = 0; k < 16; ++k) pp += wv[k]*hv[k];
        pp = wred(pp);
        float logit = pp + out_b[row];
        if (lane == 0) __builtin_nontemporal_store(logit, &orow[row]);  // keep LLC for out_w
        unsigned bbits = __float_as_uint(logit);
        unsigned key = bbits ^ ((unsigned)(((int)bbits) >> 31) | 0x80000000u);
        u64 pk = ((u64)key << 32) | (u64)(unsigned)(~row);  // smaller row wins ties
        if (pk > best) best = pk;
      }
      if (lane == 0) sbest[wid] = best;
      __syncthreads();
      if (tid == 0){
        u64 m = sbest[0];
        #pragma unroll
        for (int q = 1; q < 8; ++q) if (sbest[q] > m) m = sbest[q];
        __hip_atomic_store(&parts[wg], m, __ATOMIC_RELAXED, __HIP_MEMORY_SCOPE_AGENT);
      }
    }
    ph++; gbar(arrive, bcast, ph);
  }
}

// ---------- final log-softmax over rows (row 0 = log_softmax(zeros)) ----------
__global__ void lsm_kernel(float* __restrict__ out){
  __shared__ float red[256];
  const int row = blockIdx.x, tid = threadIdx.x;
  float* r = out + (size_t)row*NV;
  if (row == 0){
    const float v = -logf((float)NV);
    for (int i = tid; i < NV; i += 256) r[i] = v;
    return;
  }
  float m = -1e30f;
  for (int i = tid; i < NV; i += 256) m = fmaxf(m, r[i]);
  red[tid] = m; __syncthreads();
  for (int st = 128; st; st >>= 1){ if (tid < st) red[tid] = fmaxf(red[tid], red[tid+st]); __syncthreads(); }
  m = red[0]; __syncthreads();
  float s = 0.f;
  for (int i = tid; i < NV; i += 256) s += expf(r[i] - m);
  red[tid] = s; __syncthreads();
  for (int st = 128; st; st >>= 1){ if (tid < st) red[tid] += red[tid+st]; __syncthreads(); }
  const float lse = m + logf(red[0]);
  __syncthreads();
  for (int i = tid; i < NV; i += 256) r[i] -= lse;
}

extern "C" void kernel_launch(void* const* d_in, const int* in_sizes, int n_in,
                              void* d_out, int out_size, void* d_ws, size_t ws_size,
                              hipStream_t stream)
{
  (void)in_sizes; (void)n_in; (void)out_size; (void)ws_size;
  const int*   x     = (const int*)  d_in[0];
  const int*   y     = (const int*)  d_in[1];
  const float* emb   = (const float*)d_in[2];
  const float* eWih0 = (const float*)d_in[3];
  const float* eWhh0 = (const float*)d_in[4];
  const float* eb0   = (const float*)d_in[5];
  const float* eWih1 = (const float*)d_in[6];
  const float* eWhh1 = (const float*)d_in[7];
  const float* eb1   = (const float*)d_in[8];
  const float* fc1w  = (const float*)d_in[9];
  const float* fc1b  = (const float*)d_in[10];
  const float* fc2w  = (const float*)d_in[11];
  const float* fc2b  = (const float*)d_in[12];
  const float* dWih0 = (const float*)d_in[13];
  const float* dWhh0 = (const float*)d_in[14];
  const float* db0   = (const float*)d_in[15];
  const float* dWih1 = (const float*)d_in[16];
  const float* dWhh1 = (const float*)d_in[17];
  const float* db1   = (const float*)d_in[18];
  const float* out_w = (const float*)d_in[19];
  const float* out_b = (const float*)d_in[20];
  float* out = (float*)d_out;
  char* ws = (char*)d_ws;

  hipMemsetAsync(ws, 0, 33792, stream);   // zero arrive flags + bcast slots
  enc_kernel<<<dim3(NWG), dim3(TPB), 0, stream>>>(x, emb, eWih0, eWhh0, eb0,
                                                  eWih1, eWhh1, eb1,
                                                  fc1w, fc1b, fc2w, fc2b, ws);
  dec_kernel<<<dim3(NWG), dim3(TPB), 0, stream>>>(y, dWih0, dWhh0, db0,
                                                  dWih1, dWhh1, db1,
                                                  out_w, out_b, out, ws);
  lsm_kernel<<<dim3(NTY), dim3(256), 0, stream>>>(out);
}

// Round 3
// 35078.018 us; speedup vs baseline: 2.8326x; 2.8326x over previous
//
#include <hip/hip_runtime.h>
#include <cmath>

#define NV 32000
#define NE 512
#define NH 1024
#define NTX 2048
#define NTY 512
#define NWG 256
#define TPB 512

// encoder uses phases 1 .. NTX+3 (init + 2049 loop + fc1); decoder continues after
#define ENC_PH ((unsigned)(NTX + 3))

typedef float vf4 __attribute__((ext_vector_type(4)));
typedef unsigned uv4 __attribute__((ext_vector_type(4)));
typedef unsigned long long u64;
typedef unsigned long long uv2 __attribute__((ext_vector_type(2)));

// ---------- helpers ----------
__device__ inline float sigm(float x){ return 1.0f/(1.0f + expf(-x)); }

__device__ inline float wred(float v){
  #pragma unroll
  for (int m = 32; m; m >>= 1) v += __shfl_xor(v, m, 64);
  return v;
}

__device__ inline void sto(float* p, float v){
  __hip_atomic_store(p, v, __ATOMIC_RELAXED, __HIP_MEMORY_SCOPE_AGENT);
}

// Coherent (LLC-direct, sc0 sc1) read of a 1024-float state vector.
// Lane l receives elements { g*256 + l*4 + c : g=0..3, c=0..3 } in h[g][c].
// 4 x dwordx4, 16B lane stride -> 4 lanes/64B line -> 64 full-line requests
// per wave (vs 1024 4B hits for the old per-dword atomic-load pattern).
__device__ inline void cohv16(const float* base, vf4* h){
  const float* p = base + (threadIdx.x & 63)*4;
  asm volatile(
    "global_load_dwordx4 %0, %4, off sc0 sc1\n\t"
    "global_load_dwordx4 %1, %4, off offset:1024 sc0 sc1\n\t"
    "global_load_dwordx4 %2, %4, off offset:2048 sc0 sc1\n\t"
    "global_load_dwordx4 %3, %4, off offset:3072 sc0 sc1\n\t"
    "s_waitcnt vmcnt(0)"
    : "=&v"(h[0]), "=&v"(h[1]), "=&v"(h[2]), "=&v"(h[3])
    : "v"(p) : "memory");
}

// coherent read of 4 u64 argmax partials per lane (parts[4l .. 4l+3])
__device__ inline void cohp4(const u64* base, u64* d){
  const u64* p = base + (threadIdx.x & 63)*4;
  uv2 a, b;
  asm volatile(
    "global_load_dwordx4 %0, %2, off sc0 sc1\n\t"
    "global_load_dwordx4 %1, %2, off offset:16 sc0 sc1\n\t"
    "s_waitcnt vmcnt(0)"
    : "=&v"(a), "=&v"(b) : "v"(p) : "memory");
  d[0] = a[0]; d[1] = a[1]; d[2] = b[0]; d[3] = b[1];
}

// grid barrier v4: flat distributed flags (r1 design, best measured), but
//  - poll is ONE dwordx4 sc0/sc1 per lane (4 flags), RELAXED (no per-poll inv)
//  - no acquire fence at exit: all cross-WG data reads use sc0/sc1 LLC-direct
//    loads, so no cache maintenance is needed (keeps out_w warm in L2).
__device__ inline void gbar(unsigned* flags, unsigned ph){
  __syncthreads();
  if (threadIdx.x == 0)
    __hip_atomic_store(&flags[blockIdx.x], ph, __ATOMIC_RELEASE, __HIP_MEMORY_SCOPE_AGENT);
  if (threadIdx.x < 64){
    const unsigned* p = flags + threadIdx.x*4;
    for (;;){
      uv4 f;
      asm volatile("global_load_dwordx4 %0, %1, off sc0 sc1\n\ts_waitcnt vmcnt(0)"
                   : "=&v"(f) : "v"(p) : "memory");
      if (__all((int)(f[0] >= ph && f[1] >= ph && f[2] >= ph && f[3] >= ph))) break;
      __builtin_amdgcn_s_sleep(2);
    }
  }
  __syncthreads();
}

// ws layout (bytes):
//   0    : flags[256] u32 (1 KB)
//   1024 : h0buf[2][1024] f32 (8 KB)
//   9216 : h1buf[2][1024] f32 (8 KB)
//   17408: ysbuf[2][1024] f32 (8 KB)
//   25600: f1buf[1024] f32 (4 KB)
//   29696: f2buf[1024] f32 (4 KB)
//   33792: parts[256] u64 (2 KB)

// ---------- encoder: persistent, layers 0/1 pipelined, + fc1/fc2 ----------
__global__ __launch_bounds__(TPB, 2) void enc_kernel(
    const int* __restrict__ x, const float* __restrict__ emb,
    const float* __restrict__ Wih0, const float* __restrict__ Whh0, const float* __restrict__ b0,
    const float* __restrict__ Wih1, const float* __restrict__ Whh1, const float* __restrict__ b1,
    const float* __restrict__ fc1w, const float* __restrict__ fc1b,
    const float* __restrict__ fc2w, const float* __restrict__ fc2b,
    char* __restrict__ ws)
{
  unsigned* flags = (unsigned*)ws;
  float* h0buf = (float*)(ws + 1024);
  float* h1buf = h0buf + 2048;
  float* ysbuf = h1buf + 2048;
  float* f1buf = ysbuf + 2048;
  float* f2buf = f1buf + 1024;

  const int tid = threadIdx.x, wg = blockIdx.x;
  const int wid = tid >> 6, lane = tid & 63;
  const bool isA = (wid < 4);          // waves 0-3: layer0, waves 4-7: layer1
  const int j = wg*4 + (wid & 3);      // 0..1023 : hidden row owned by this wave
  unsigned ph = 0;

  // register-resident weights, permuted to the vec4-coalesced lane layout:
  // wa[g][q][c] = W[j + g*1024][q*256 + lane*4 + c]
  vf4 wa[4][4], wb[4][4];
  float bias[4];
  if (isA){
    #pragma unroll
    for (int g = 0; g < 4; ++g){
      const float* r = Whh0 + (size_t)(j + g*1024)*1024 + lane*4;
      #pragma unroll
      for (int q = 0; q < 4; ++q) wa[g][q] = *(const vf4*)(r + q*256);
      const float* r2 = Wih0 + (size_t)(j + g*1024)*512 + lane*4;
      wb[g][0] = *(const vf4*)(r2);
      wb[g][1] = *(const vf4*)(r2 + 256);
      wb[g][2] = vf4{0.f,0.f,0.f,0.f};
      wb[g][3] = vf4{0.f,0.f,0.f,0.f};
      bias[g] = b0[j + g*1024];
    }
  } else {
    #pragma unroll
    for (int g = 0; g < 4; ++g){
      const float* r = Wih1 + (size_t)(j + g*1024)*1024 + lane*4;
      const float* r2 = Whh1 + (size_t)(j + g*1024)*1024 + lane*4;
      #pragma unroll
      for (int q = 0; q < 4; ++q){
        wa[g][q] = *(const vf4*)(r + q*256);
        wb[g][q] = *(const vf4*)(r2 + q*256);
      }
      bias[g] = b1[j + g*1024];
    }
  }

  float c = 0.f;
  if (lane == 0){
    if (isA) sto(&h0buf[j], 0.f);
    else     sto(&h1buf[j], 0.f);
  }
  ph++; gbar(flags, ph);

  // embedding prefetch for t = 0 (vec4-coalesced layout; plain cached loads)
  vf4 xe[2] = { vf4{0,0,0,0}, vf4{0,0,0,0} };
  if (isA){
    const float* e = emb + (size_t)x[0]*NE + lane*4;
    xe[0] = *(const vf4*)e;
    xe[1] = *(const vf4*)(e + 256);
  }

  for (int t = 0; t <= NTX; ++t){
    if (isA){
      if (t < NTX){
        vf4 hs[4]; cohv16(h0buf + (t&1)*1024, hs);
        vf4 xc[2] = { xe[0], xe[1] };
        if (t + 1 < NTX){    // prefetch next embedding row
          const float* e = emb + (size_t)x[t+1]*NE + lane*4;
          xe[0] = *(const vf4*)e;
          xe[1] = *(const vf4*)(e + 256);
        }
        float p[4];
        #pragma unroll
        for (int g = 0; g < 4; ++g){
          vf4 acc = wa[g][0]*hs[0];
          acc += wa[g][1]*hs[1];
          acc += wa[g][2]*hs[2];
          acc += wa[g][3]*hs[3];
          acc += wb[g][0]*xc[0];
          acc += wb[g][1]*xc[1];
          p[g] = acc.x + acc.y + acc.z + acc.w;
        }
        #pragma unroll
        for (int g = 0; g < 4; ++g) p[g] = wred(p[g]) + bias[g];
        float ig = sigm(p[0]), fg = sigm(p[1]), gg = tanhf(p[2]), og = sigm(p[3]);
        c = fg*c + ig*gg;
        float hn = og * tanhf(c);
        if (lane == 0){
          sto(&h0buf[((t&1)^1)*1024 + j], hn);
          sto(&ysbuf[(t&1)*1024 + j], hn);
        }
      }
    } else {
      if (t >= 1){
        const int t1 = t - 1;
        vf4 ys[4]; cohv16(ysbuf + (t1&1)*1024, ys);
        vf4 hs[4]; cohv16(h1buf + (t1&1)*1024, hs);
        float p[4];
        #pragma unroll
        for (int g = 0; g < 4; ++g){
          vf4 acc = wa[g][0]*ys[0];
          acc += wa[g][1]*ys[1];
          acc += wa[g][2]*ys[2];
          acc += wa[g][3]*ys[3];
          acc += wb[g][0]*hs[0];
          acc += wb[g][1]*hs[1];
          acc += wb[g][2]*hs[2];
          acc += wb[g][3]*hs[3];
          p[g] = acc.x + acc.y + acc.z + acc.w;
        }
        #pragma unroll
        for (int g = 0; g < 4; ++g) p[g] = wred(p[g]) + bias[g];
        float ig = sigm(p[0]), fg = sigm(p[1]), gg = tanhf(p[2]), og = sigm(p[3]);
        c = fg*c + ig*gg;
        float hn = og * tanhf(c);
        if (lane == 0) sto(&h1buf[((t1&1)^1)*1024 + j], hn);
      }
    }
    ph++; gbar(flags, ph);
  }

  // fc1: h_last is h1buf parity 0 (last write t1=2047 -> wp=0)
  if (isA){
    vf4 hs[4]; cohv16(h1buf, hs);
    const float* r = fc1w + (size_t)j*1024 + lane*4;
    vf4 acc = (*(const vf4*)(r      ))*hs[0];
    acc    += (*(const vf4*)(r + 256))*hs[1];
    acc    += (*(const vf4*)(r + 512))*hs[2];
    acc    += (*(const vf4*)(r + 768))*hs[3];
    float s = wred(acc.x + acc.y + acc.z + acc.w) + fc1b[j];
    if (lane == 0) sto(&f1buf[j], fmaxf(s, 0.f));
  }
  ph++; gbar(flags, ph);
  if (isA){
    vf4 fs[4]; cohv16(f1buf, fs);
    const float* r = fc2w + (size_t)j*1024 + lane*4;
    vf4 acc = (*(const vf4*)(r      ))*fs[0];
    acc    += (*(const vf4*)(r + 256))*fs[1];
    acc    += (*(const vf4*)(r + 512))*fs[2];
    acc    += (*(const vf4*)(r + 768))*fs[3];
    float s = wred(acc.x + acc.y + acc.z + acc.w) + fc2b[j];
    if (lane == 0) sto(&f2buf[j], fmaxf(s, 0.f));
  }
  // f2buf visibility to dec_kernel: kernel dispatch boundary (stream-ordered)
}

// ---------- decoder: persistent, 511 greedy steps ----------
__global__ __launch_bounds__(TPB, 2) void dec_kernel(
    const int* __restrict__ y,
    const float* __restrict__ dWih0, const float* __restrict__ dWhh0, const float* __restrict__ db0,
    const float* __restrict__ dWih1, const float* __restrict__ dWhh1, const float* __restrict__ db1,
    const float* __restrict__ out_w, const float* __restrict__ out_b,
    float* __restrict__ out, char* __restrict__ ws)
{
  unsigned* flags = (unsigned*)ws;     // continue encoder's monotonic phases
  float* h0buf = (float*)(ws + 1024);
  float* h1buf = h0buf + 2048;
  float* f2buf = h1buf + 2048 + 2048 + 1024;      // skip ysbuf, f1buf
  u64* parts   = (u64*)(ws + 33792);

  const int tid = threadIdx.x, wg = blockIdx.x;
  const int wid = tid >> 6, lane = tid & 63;
  const bool isA = (wid < 4);
  const int j = wg*4 + (wid & 3);
  unsigned ph = ENC_PH;                // encoder's final flag value

  vf4 wa[4][4], wb[4][4];
  float bias[4], wx[4];
  if (isA){
    #pragma unroll
    for (int g = 0; g < 4; ++g){
      const float* r = dWhh0 + (size_t)(j + g*1024)*1024 + lane*4;
      #pragma unroll
      for (int q = 0; q < 4; ++q) wa[g][q] = *(const vf4*)(r + q*256);
      wx[g]   = dWih0[j + g*1024];
      bias[g] = db0[j + g*1024];
    }
  } else {
    #pragma unroll
    for (int g = 0; g < 4; ++g){
      const float* r = dWih1 + (size_t)(j + g*1024)*1024 + lane*4;
      const float* r2 = dWhh1 + (size_t)(j + g*1024)*1024 + lane*4;
      #pragma unroll
      for (int q = 0; q < 4; ++q){
        wa[g][q] = *(const vf4*)(r + q*256);
        wb[g][q] = *(const vf4*)(r2 + q*256);
      }
      bias[g] = db1[j + g*1024];
      wx[g] = 0.f;
    }
  }

  float c = f2buf[j];                 // h and c both init to f2
  if (lane == 0){
    if (isA) sto(&h0buf[j], c);
    else     sto(&h1buf[j], c);
  }
  const float y0f = (float)y[0];
  ph++; gbar(flags, ph);

  __shared__ u64 sbest[8];

  for (int s = 0; s < NTY - 1; ++s){
    const int rp = s & 1, wp = rp ^ 1;

    // ---- phase A: layer0 cell (group A) ----
    if (isA){
      float xt;
      if (s == 0) xt = y0f;
      else {
        // redundant argmax reduction of 256 WG-partials (written last phase C)
        u64 q4[4]; cohp4(parts, q4);
        u64 b = q4[0];
        if (q4[1] > b) b = q4[1];
        if (q4[2] > b) b = q4[2];
        if (q4[3] > b) b = q4[3];
        #pragma unroll
        for (int m = 32; m; m >>= 1){
          u64 v = __shfl_xor(b, m, 64);
          if (v > b) b = v;
        }
        unsigned row = ~(unsigned)(b & 0xFFFFFFFFull);
        xt = (float)row;
      }
      vf4 hs[4]; cohv16(h0buf + rp*1024, hs);
      float p[4];
      #pragma unroll
      for (int g = 0; g < 4; ++g){
        vf4 acc = wa[g][0]*hs[0];
        acc += wa[g][1]*hs[1];
        acc += wa[g][2]*hs[2];
        acc += wa[g][3]*hs[3];
        p[g] = acc.x + acc.y + acc.z + acc.w;
      }
      #pragma unroll
      for (int g = 0; g < 4; ++g) p[g] = wred(p[g]) + wx[g]*xt + bias[g];
      float ig = sigm(p[0]), fg = sigm(p[1]), gg = tanhf(p[2]), og = sigm(p[3]);
      c = fg*c + ig*gg;
      float hn = og * tanhf(c);
      if (lane == 0) sto(&h0buf[wp*1024 + j], hn);
    }
    ph++; gbar(flags, ph);

    // ---- phase B: layer1 cell (group B) ----
    if (!isA){
      vf4 u[4];  cohv16(h0buf + wp*1024, u);
      vf4 hs[4]; cohv16(h1buf + rp*1024, hs);
      float p[4];
      #pragma unroll
      for (int g = 0; g < 4; ++g){
        vf4 acc = wa[g][0]*u[0];
        acc += wa[g][1]*u[1];
        acc += wa[g][2]*u[2];
        acc += wa[g][3]*u[3];
        acc += wb[g][0]*hs[0];
        acc += wb[g][1]*hs[1];
        acc += wb[g][2]*hs[2];
        acc += wb[g][3]*hs[3];
        p[g] = acc.x + acc.y + acc.z + acc.w;
      }
      #pragma unroll
      for (int g = 0; g < 4; ++g) p[g] = wred(p[g]) + bias[g];
      float ig = sigm(p[0]), fg = sigm(p[1]), gg = tanhf(p[2]), og = sigm(p[3]);
      c = fg*c + ig*gg;
      float hn = og * tanhf(c);
      if (lane == 0) sto(&h1buf[wp*1024 + j], hn);
    }
    ph++; gbar(flags, ph);

    // ---- phase C: logits row matvecs + partial argmax (all waves) ----
    {
      vf4 hv[4]; cohv16(h1buf + wp*1024, hv);
      u64 best = 0ull;
      float* orow = out + (size_t)(s + 1)*NV;
      for (int idx = wid; idx < 125; idx += 8){
        const int row = wg*125 + idx;
        const float* r = out_w + (size_t)row*1024 + lane*4;
        vf4 acc = (*(const vf4*)(r      ))*hv[0];
        acc    += (*(const vf4*)(r + 256))*hv[1];
        acc    += (*(const vf4*)(r + 512))*hv[2];
        acc    += (*(const vf4*)(r + 768))*hv[3];
        float pp = wred(acc.x + acc.y + acc.z + acc.w);
        float logit = pp + out_b[row];
        if (lane == 0) orow[row] = logit;
        unsigned bbits = __float_as_uint(logit);
        unsigned key = bbits ^ ((unsigned)(((int)bbits) >> 31) | 0x80000000u);
        u64 pk = ((u64)key << 32) | (u64)(unsigned)(~row);  // smaller row wins ties
        if (pk > best) best = pk;
      }
      if (lane == 0) sbest[wid] = best;
      __syncthreads();
      if (tid == 0){
        u64 m = sbest[0];
        #pragma unroll
        for (int q = 1; q < 8; ++q) if (sbest[q] > m) m = sbest[q];
        __hip_atomic_store(&parts[wg], m, __ATOMIC_RELAXED, __HIP_MEMORY_SCOPE_AGENT);
      }
    }
    ph++; gbar(flags, ph);
  }
}

// ---------- final log-softmax over rows (row 0 = log_softmax(zeros)) ----------
__global__ void lsm_kernel(float* __restrict__ out){
  __shared__ float red[256];
  const int row = blockIdx.x, tid = threadIdx.x;
  float* r = out + (size_t)row*NV;
  if (row == 0){
    const float v = -logf((float)NV);
    for (int i = tid; i < NV; i += 256) r[i] = v;
    return;
  }
  float m = -1e30f;
  for (int i = tid; i < NV; i += 256) m = fmaxf(m, r[i]);
  red[tid] = m; __syncthreads();
  for (int st = 128; st; st >>= 1){ if (tid < st) red[tid] = fmaxf(red[tid], red[tid+st]); __syncthreads(); }
  m = red[0]; __syncthreads();
  float s = 0.f;
  for (int i = tid; i < NV; i += 256) s += expf(r[i] - m);
  red[tid] = s; __syncthreads();
  for (int st = 128; st; st >>= 1){ if (tid < st) red[tid] += red[tid+st]; __syncthreads(); }
  const float lse = m + logf(red[0]);
  __syncthreads();
  for (int i = tid; i < NV; i += 256) r[i] -= lse;
}

extern "C" void kernel_launch(void* const* d_in, const int* in_sizes, int n_in,
                              void* d_out, int out_size, void* d_ws, size_t ws_size,
                              hipStream_t stream)
{
  (void)in_sizes; (void)n_in; (void)out_size; (void)ws_size;
  const int*   x     = (const int*)  d_in[0];
  const int*   y     = (const int*)  d_in[1];
  const float* emb   = (const float*)d_in[2];
  const float* eWih0 = (const float*)d_in[3];
  const float* eWhh0 = (const float*)d_in[4];
  const float* eb0   = (const float*)d_in[5];
  const float* eWih1 = (const float*)d_in[6];
  const float* eWhh1 = (const float*)d_in[7];
  const float* eb1   = (const float*)d_in[8];
  const float* fc1w  = (const float*)d_in[9];
  const float* fc1b  = (const float*)d_in[10];
  const float* fc2w  = (const float*)d_in[11];
  const float* fc2b  = (const float*)d_in[12];
  const float* dWih0 = (const float*)d_in[13];
  const float* dWhh0 = (const float*)d_in[14];
  const float* db0   = (const float*)d_in[15];
  const float* dWih1 = (const float*)d_in[16];
  const float* dWhh1 = (const float*)d_in[17];
  const float* db1   = (const float*)d_in[18];
  const float* out_w = (const float*)d_in[19];
  const float* out_b = (const float*)d_in[20];
  float* out = (float*)d_out;
  char* ws = (char*)d_ws;

  hipMemsetAsync(ws, 0, 1024, stream);   // zero the 256 phase flags
  enc_kernel<<<dim3(NWG), dim3(TPB), 0, stream>>>(x, emb, eWih0, eWhh0, eb0,
                                                  eWih1, eWhh1, eb1,
                                                  fc1w, fc1b, fc2w, fc2b, ws);
  dec_kernel<<<dim3(NWG), dim3(TPB), 0, stream>>>(y, dWih0, dWhh0, db0,
                                                  dWih1, dWhh1, db1,
                                                  out_w, out_b, out, ws);
  lsm_kernel<<<dim3(NTY), dim3(256), 0, stream>>>(out);
}